// Round 10
// baseline (1572.524 us; speedup 1.0000x reference)
//
#include <hip/hip_runtime.h>

#define B_    2
#define N_    4096
#define E_    262144
#define F_    5
#define ED    150
#define ND    100
#define NIN   154
#define EIN   9
#define GN    16      // nodes per block; grid = 8192/16 = 512 blocks = 2/CU resident
#define HSTR  168     // ushort stride (336B = 21x16B odd) -> conflict-free b128
#define NSTR  164     // f32 stride (656B = 41x16B odd) -> conflict-free tail reads
#define ASTR  116     // f32 stride (464B = 29x16B odd)
#define CSTR  104

typedef __attribute__((ext_vector_type(8)))  short bf16x8;
typedef __attribute__((ext_vector_type(16))) float f32x16;
typedef __attribute__((ext_vector_type(4)))  float f4;

static __device__ __forceinline__ unsigned short f2bf(float x) {
    unsigned int u = __float_as_uint(x);
    return (unsigned short)((u + 0x7fffu + ((u >> 16) & 1u)) >> 16);
}
static __device__ __forceinline__ float bf2f(unsigned short s) {
    return __uint_as_float(((unsigned int)s) << 16);
}

struct __align__(16) SMem {
    union {
        struct {
            unsigned short h_hi[64][HSTR];   // 21504 B  layer-1 out split-hi
            unsigned short h_lo[64][HSTR];   // 21504 B
        } lp;                                 // 43008 B (main loop)
        struct {
            float hA[32][ASTR];              // 14848 B
            float hB[32][ASTR];              // 14848 B
            float hC[32][CSTR];              // 13312 B
        } tl;                                 // 43008 B (tail aliases loop region)
    } u;
    float nin[32][NSTR];                     // 20992 B  (rows 16..31 stay zero; M=32 tail tile)
};                                            // 64000 B -> 2 blocks/CU (thread-slot limited)

// pre-kernel: pack split-bf16 W2 into ws as u32 (hi | lo<<16), k-major [160][160], zero-padded
__global__ void prep_w2(const float* __restrict__ eW2, unsigned int* __restrict__ wp) {
    int i = blockIdx.x * 256 + threadIdx.x;
    if (i >= 160 * 160) return;
    int k = i / 160, n = i - k * 160;
    unsigned int v = 0;
    if (k < ED && n < ED) {
        float w = eW2[k * ED + n];
        unsigned short hi = f2bf(w);
        unsigned short lo = f2bf(w - bf2f(hi));
        v = (unsigned int)hi | ((unsigned int)lo << 16);
    }
    wp[i] = v;
}

// one tail MLP layer for 32 rows (16 real nodes + 16 zero rows): Y = relu(X @ Wg + bias)
template<int KS, int KR, int XS, int YS>
static __device__ __forceinline__ void tail_layer(const float* __restrict__ X,
                                                  float* __restrict__ Y,
                                                  const float* __restrict__ Wg,
                                                  const float* __restrict__ bias,
                                                  int wave, int lane)
{
    if (wave >= 4) return;
    const int jc  = wave * 32 + (lane & 31);
    const int hi  = lane >> 5;
    const int row = lane & 31;
    f32x16 C;
    #pragma unroll
    for (int r = 0; r < 16; ++r) C[r] = 0.0f;
    #pragma unroll
    for (int s = 0; s < KS; ++s) {
        bf16x8 ah, al, bhv, blv;
        f4 xa = *(const f4*)&X[row * XS + s * 16 + 4 * hi];
        f4 xb = *(const f4*)&X[row * XS + s * 16 + 8 + 4 * hi];
        #pragma unroll
        for (int e = 0; e < 8; ++e) {
            float x = (e < 4) ? xa[e] : xb[e - 4];
            unsigned short h = f2bf(x);
            ah[e] = (short)h;  al[e] = (short)f2bf(x - bf2f(h));
            int k = s * 16 + (e & 3) + 8 * (e >> 2) + 4 * hi;
            float w = (k < KR && jc < ND) ? Wg[k * ND + jc] : 0.0f;
            unsigned short wh = f2bf(w);
            bhv[e] = (short)wh;  blv[e] = (short)f2bf(w - bf2f(wh));
        }
        C = __builtin_amdgcn_mfma_f32_32x32x16_bf16(ah, bhv, C, 0, 0, 0);
        C = __builtin_amdgcn_mfma_f32_32x32x16_bf16(ah, blv, C, 0, 0, 0);
        C = __builtin_amdgcn_mfma_f32_32x32x16_bf16(al, bhv, C, 0, 0, 0);
    }
    if (jc < ND) {
        float bv = bias[jc];
        #pragma unroll
        for (int r = 0; r < 16; ++r) {
            int node = (r & 3) + 8 * (r >> 2) + 4 * hi;
            Y[node * YS + jc] = fmaxf(C[r] + bv, 0.0f);
        }
    }
}

__global__ __launch_bounds__(512, 1)
void deltagn_v10(const float* __restrict__ V,  const float* __restrict__ dt,
                 const float* __restrict__ eW1, const float* __restrict__ eb1,
                 const unsigned int* __restrict__ wp,  // packed split W2 from ws
                 const float* __restrict__ eb2,
                 const float* __restrict__ nW1, const float* __restrict__ nb1,
                 const float* __restrict__ nW2, const float* __restrict__ nb2,
                 const float* __restrict__ nW3, const float* __restrict__ nb3,
                 const float* __restrict__ lW,  const float* __restrict__ lb,
                 const int* __restrict__ Rs,   const int* __restrict__ Rr,
                 float* __restrict__ out)
{
    __shared__ SMem sm;
    const int t    = threadIdx.x;
    const int wave = t >> 6;
    const int lane = t & 63;
    const int blk  = blockIdx.x;
    const int b    = blk >> 8;            // 256 blocks per batch
    const int n0   = (blk & 255) * GN;
    const float HALF = 3.0f, BOXF = 6.0f;
    const float dtv = dt[b];

    // int64-vs-int32 index detection (values < 4096 => odd int32 words all zero iff int64)
    const bool i64S = (__ballot(Rs[2 * lane + 1] == 0) == ~0ull);
    const bool i64R = (__ballot(Rr[2 * lane + 1] == 0) == ~0ull);

    // ---- zero nin (all 32 rows incl. pads) ----
    {
        float* nf = &sm.nin[0][0];
        for (int i = t; i < 32 * NSTR; i += 512) nf[i] = 0.0f;
    }

    float b2v = 0.0f;
    if (wave < 5) {
        const int col = wave * 32 + (lane & 31);
        b2v = (col < ED) ? eb2[col] : 0.0f;
    }
    __syncthreads();

    // phase-B: one 16-col kstep of h = relu(Ein @ eW1 + eb1), split+pack to LDS
    auto phaseB = [&](const float (&ein)[EIN], int ks) {
        const int sb = ks * 16;
        float hv[16];
        #pragma unroll
        for (int r = 0; r < 16; ++r) {
            const int c  = sb + r;
            const int cs = (c < ED) ? c : 0;
            float a = eb1[cs];
            #pragma unroll
            for (int q = 0; q < EIN; ++q) a += ein[q] * eW1[q * ED + cs];
            hv[r] = (c < ED) ? fmaxf(a, 0.0f) : 0.0f;
        }
        constexpr int rm0[8] = {0,1,2,3,8,9,10,11};
        constexpr int rm1[8] = {4,5,6,7,12,13,14,15};
        bf16x8 h0, h1, l0, l1;
        #pragma unroll
        for (int e = 0; e < 8; ++e) {
            float x0 = hv[rm0[e]], x1 = hv[rm1[e]];
            unsigned short a0 = f2bf(x0), a1 = f2bf(x1);
            h0[e] = (short)a0;  l0[e] = (short)f2bf(x0 - bf2f(a0));
            h1[e] = (short)a1;  l1[e] = (short)f2bf(x1 - bf2f(a1));
        }
        *(bf16x8*)&sm.u.lp.h_hi[lane][sb + 0] = h0;
        *(bf16x8*)&sm.u.lp.h_hi[lane][sb + 8] = h1;
        *(bf16x8*)&sm.u.lp.h_lo[lane][sb + 0] = l0;
        *(bf16x8*)&sm.u.lp.h_lo[lane][sb + 8] = l1;
    };

    // ======== main loop: P (all 8 waves produce h) -> C (waves 0-4 MFMA, B from L2) ========
    for (int g = 0; g < GN; ++g) {
        { // ---- phase P ----
            float ein[EIN];
            const int eb = b * E_ + (n0 + g) * 64 + lane;
            const int si = i64S ? Rs[2 * eb] : Rs[eb];
            const int ri = i64R ? Rr[2 * eb] : Rr[eb];
            const float* vs = V + (b * N_ + si) * F_;
            const float* vr = V + (b * N_ + ri) * F_;
            float d0 = vs[1] - vr[1], d1 = vs[2] - vr[2];
            d0 = (d0 >  HALF) ? d0 - BOXF : d0;
            d0 = (d0 <= -HALF) ? d0 + BOXF : d0;
            d1 = (d1 >  HALF) ? d1 - BOXF : d1;
            d1 = (d1 <= -HALF) ? d1 + BOXF : d1;
            ein[0] = vs[0]; ein[1] = vs[3]; ein[2] = vs[4];
            ein[3] = vr[0]; ein[4] = vr[3]; ein[5] = vr[4];
            ein[6] = d0;    ein[7] = d1;    ein[8] = dtv;

            phaseB(ein, wave);                      // ksteps 0..7
            if (wave < 2) phaseB(ein, wave + 8);    // ksteps 8,9
            if (wave == 7 && lane < 4) {            // nin extras for node g
                const int bn5 = (b * N_ + n0 + g) * F_;
                if (lane == 0) sm.nin[g][0]       = V[bn5 + 0];
                if (lane == 1) sm.nin[g][1]       = V[bn5 + 3];
                if (lane == 2) sm.nin[g][2]       = V[bn5 + 4];
                if (lane == 3) sm.nin[g][NIN - 1] = dtv;
            }
        }
        __syncthreads();

        if (wave < 5) { // ---- phase C: edge GEMM, A from LDS, B streamed from L2 ----
            const int row  = lane & 31;
            const int hi   = lane >> 5;
            const int col  = wave * 32 + row;
            const int eoff = hi * 8;
            f32x16 C0, C1;
            #pragma unroll
            for (int r = 0; r < 16; ++r) { C0[r] = 0.0f; C1[r] = 0.0f; }
            #pragma unroll
            for (int s = 0; s < 10; ++s) {
                const int cb = s * 16 + eoff;
                bf16x8 bhv, blv;
                #pragma unroll
                for (int e = 0; e < 8; ++e) {
                    const int kk = s * 16 + (e & 3) + 8 * (e >> 2) + 4 * hi;
                    unsigned int v = wp[kk * 160 + col];   // coalesced, L2-hot
                    bhv[e] = (short)(v & 0xffffu);
                    blv[e] = (short)(v >> 16);
                }
                bf16x8 ah0 = *(const bf16x8*)&sm.u.lp.h_hi[row     ][cb];
                bf16x8 al0 = *(const bf16x8*)&sm.u.lp.h_lo[row     ][cb];
                bf16x8 ah1 = *(const bf16x8*)&sm.u.lp.h_hi[row + 32][cb];
                bf16x8 al1 = *(const bf16x8*)&sm.u.lp.h_lo[row + 32][cb];
                C0 = __builtin_amdgcn_mfma_f32_32x32x16_bf16(ah0, bhv, C0, 0, 0, 0);
                C1 = __builtin_amdgcn_mfma_f32_32x32x16_bf16(ah1, bhv, C1, 0, 0, 0);
                C0 = __builtin_amdgcn_mfma_f32_32x32x16_bf16(ah0, blv, C0, 0, 0, 0);
                C1 = __builtin_amdgcn_mfma_f32_32x32x16_bf16(ah1, blv, C1, 0, 0, 0);
                C0 = __builtin_amdgcn_mfma_f32_32x32x16_bf16(al0, bhv, C0, 0, 0, 0);
                C1 = __builtin_amdgcn_mfma_f32_32x32x16_bf16(al1, bhv, C1, 0, 0, 0);
            }
            float colsum = 0.0f;
            #pragma unroll
            for (int r = 0; r < 16; ++r)
                colsum += fmaxf(C0[r] + b2v, 0.0f) + fmaxf(C1[r] + b2v, 0.0f);
            colsum += __shfl_xor(colsum, 32);
            if (lane < 32 && col < ED) sm.nin[g][3 + col] = colsum;
        }
        __syncthreads();
    }

    // ---- zero hA/hB k-pads (aliased region free now; disjoint from tail1 writes) ----
    for (int i = t; i < 32 * 16; i += 512) {
        sm.u.tl.hA[i >> 4][100 + (i & 15)] = 0.0f;
        sm.u.tl.hB[i >> 4][100 + (i & 15)] = 0.0f;
    }

    // ======== tail: batched node-MLP (M=32 tile; rows 16..31 are zeros) ========
    tail_layer<10, NIN, NSTR, ASTR>(&sm.nin[0][0],    &sm.u.tl.hA[0][0], nW1, nb1, wave, lane);
    __syncthreads();
    tail_layer<7, ND, ASTR, ASTR>(&sm.u.tl.hA[0][0], &sm.u.tl.hB[0][0], nW2, nb2, wave, lane);
    __syncthreads();
    tail_layer<7, ND, ASTR, CSTR>(&sm.u.tl.hB[0][0], &sm.u.tl.hC[0][0], nW3, nb3, wave, lane);
    __syncthreads();

    // ---- head: 16 nodes x 4 outputs on threads 0..63 ----
    if (t < GN * 4) {
        const int node = t >> 2, o = t & 3;
        float a = lb[o];
        #pragma unroll 10
        for (int k = 0; k < ND; ++k) a += sm.u.tl.hC[node][k] * lW[k * 4 + o];
        const int bn = b * N_ + n0 + node;
        float nv = V[bn * F_ + 1 + o] + a;
        if (o < 2) {
            nv = (nv >=  HALF) ? nv - BOXF : nv;
            nv = (nv <  -HALF) ? nv + BOXF : nv;
        }
        out[bn * 4 + o] = nv;
    }
}

extern "C" void kernel_launch(void* const* d_in, const int* in_sizes, int n_in,
                              void* d_out, int out_size, void* d_ws, size_t ws_size,
                              hipStream_t stream) {
    (void)in_sizes; (void)n_in; (void)ws_size; (void)out_size;
    const float* V   = (const float*)d_in[0];
    const float* dt  = (const float*)d_in[1];
    const float* eW1 = (const float*)d_in[2];
    const float* eb1 = (const float*)d_in[3];
    const float* eW2 = (const float*)d_in[4];
    const float* eb2 = (const float*)d_in[5];
    const float* nW1 = (const float*)d_in[6];
    const float* nb1 = (const float*)d_in[7];
    const float* nW2 = (const float*)d_in[8];
    const float* nb2 = (const float*)d_in[9];
    const float* nW3 = (const float*)d_in[10];
    const float* nb3 = (const float*)d_in[11];
    const float* lW  = (const float*)d_in[12];
    const float* lb  = (const float*)d_in[13];
    const int* Rs = (const int*)d_in[14];
    const int* Rr = (const int*)d_in[15];
    float* out = (float*)d_out;
    unsigned int* wpack = (unsigned int*)d_ws;   // 160*160*4 = 102400 B of scratch

    prep_w2<<<dim3(100), dim3(256), 0, stream>>>(eW2, wpack);
    deltagn_v10<<<dim3(512), dim3(512), 0, stream>>>(
        V, dt, eW1, eb1, wpack, eb2, nW1, nb1, nW2, nb2, nW3, nb3, lW, lb, Rs, Rr, out);
}